// Round 13
// baseline (1619.706 us; speedup 1.0000x reference)
//
#include <hip/hip_runtime.h>

#define SEQ   1024
#define BATCH 512
#define HID   128

typedef __attribute__((ext_vector_type(8))) short          short8v;
typedef __attribute__((ext_vector_type(4))) float          float4v;
typedef __attribute__((ext_vector_type(8))) unsigned short ushort8v;

__device__ __forceinline__ unsigned short f2bf(float f) {
    union { float f; unsigned u; } v; v.f = f;
    return (unsigned short)((v.u + 0x7fffu + ((v.u >> 16) & 1u)) >> 16);
}
__device__ __forceinline__ float bf2f(unsigned short u) {
    union { unsigned u; float f; } v; v.u = ((unsigned)u) << 16;
    return v.f;
}
__device__ __forceinline__ unsigned packbf(float a, float b) {
    return (unsigned)f2bf(a) | ((unsigned)f2bf(b) << 16);
}
__device__ __forceinline__ float fast_cos(float x) {
    return __builtin_amdgcn_cosf(x * 0.15915494309189535f);   // v_cos takes revolutions
}
__device__ __forceinline__ float fast_sigmoid(float x) {
    return __builtin_amdgcn_rcpf(1.0f + __builtin_amdgcn_exp2f(-1.4426950408889634f * x));
}
__device__ __forceinline__ float fast_tanh(float x) {
    return 1.0f - 2.0f * __builtin_amdgcn_rcpf(1.0f + __builtin_amdgcn_exp2f(2.8853900817779268f * x));
}
template<int CTRL, int RM>
__device__ __forceinline__ float dpp1(float v) {
    union { float f; int i; } s, o, r;
    s.f = v; o.f = 1.0f;
    r.i = __builtin_amdgcn_update_dpp(o.i, s.i, CTRL, RM, 0xf, false);
    return r.f;
}
#define BAR() do { asm volatile("s_waitcnt lgkmcnt(0)" ::: "memory");  \
                   __builtin_amdgcn_s_barrier();                       \
                   __builtin_amdgcn_sched_barrier(0); } while (0)

// in-wave inclusive cumprod over 128 cols held as (a = col kg*32+l15,
// b = col kg*32+16+l15). 16-lane DPP scans + block totals via shfl.
__device__ __forceinline__ void fscan(float a, float b, int kg,
                                      float& Fa, float& Fb) {
    float Sa = a, Sb = b;
    Sa *= dpp1<0x111, 0xf>(Sa);  Sb *= dpp1<0x111, 0xf>(Sb);   // row_shr:1
    Sa *= dpp1<0x112, 0xf>(Sa);  Sb *= dpp1<0x112, 0xf>(Sb);   // row_shr:2
    Sa *= dpp1<0x114, 0xf>(Sa);  Sb *= dpp1<0x114, 0xf>(Sb);   // row_shr:4
    Sa *= dpp1<0x118, 0xf>(Sa);  Sb *= dpp1<0x118, 0xf>(Sb);   // row_shr:8
    const float T0a = __shfl(Sa, 15), T0b = __shfl(Sb, 15);
    const float T1a = __shfl(Sa, 31), T1b = __shfl(Sb, 31);
    const float T2a = __shfl(Sa, 47), T2b = __shfl(Sb, 47);
    const float Taown = __shfl(Sa, kg * 16 + 15);
    const float p0 = T0a * T0b, p1 = T1a * T1b, p2 = T2a * T2b;
    const float rp = (kg == 0) ? 1.f : (kg == 1) ? p0
                   : (kg == 2) ? p0 * p1 : p0 * p1 * p2;
    Fa = rp * Sa;
    Fb = rp * Taown * Sb;
}

// LDS swizzles: bijective within the 128-col index; spreads kg/lane groups
// across banks so every hot access is <=2-way (free).
__device__ __forceinline__ int zswz(int slot, int g, int c) {
    return slot * 512 + g * 128 + (c ^ ((c >> 5) << 4) ^ ((slot & 2) << 3));
}
__device__ __forceinline__ int gswz(int row, int g, int c) {
    return row * 512 + g * 128 + (c ^ ((c >> 5) << 4));
}

// ---------------------------------------------------------------------------
// ONE persistent kernel. 256 WGs x 256 thr (4 waves = 1/SIMD, 512-VGPR class).
// Wave g owns gate g. Per step:
//  Phase A: 32-MFMA h-GEMM (2 batch rows replicated in M) + 4-MFMA x-tile of
//    the NEXT 8-step window (16 M-slots = 8 steps x 2 rows, ZERO waste) +
//    z-add from bf16 zring + in-register activation (wave0: full f-cumprod
//    via fscan) -> gact.  BAR.
//  Phase B: cell update, 1 (row,col)/lane across 4 waves; h_bf + out writes;
//    every 8th step: publish pre-loaded x window to x_win.  BAR.
// x-GEMM amortized cost: 4 MFMA/step/wave (was 32) -> chain ~= 36 MFMA + tails.
// ---------------------------------------------------------------------------
__global__ __launch_bounds__(256, 1) void qlstm_fused(
    const float* __restrict__ X,
    const float* __restrict__ Wf, const float* __restrict__ bfp,
    const float* __restrict__ Wi, const float* __restrict__ bip,
    const float* __restrict__ Wg, const float* __restrict__ bgp,
    const float* __restrict__ Wo, const float* __restrict__ bop,
    float* __restrict__ out)
{
    __shared__ unsigned zr_lds[16 * 4 * 128];                 // 32 KB: bf16 row-pair z ring
    __shared__ float    ga_lds[2 * 4 * 128];                  // 4 KB: activated gates
    __shared__ alignas(16) unsigned short h_bf[2][HID];       // 512 B
    __shared__ alignas(16) unsigned short x_win[2][16][HID];  // 8 KB: x window dbuf

    const int tid = threadIdx.x, lane = tid & 63, wid = tid >> 6;
    const int l15 = lane & 15, kg = lane >> 4;
    const int b0 = blockIdx.x * 2;
    const int g = wid;
    const float* Wsel = (g == 0) ? Wf : (g == 1) ? Wi : (g == 2) ? Wg : Wo;
    const float* bsel = (g == 0) ? bfp : (g == 1) ? bip : (g == 2) ? bgp : bop;

    // weight fragments: W_x (k 0..127) and W_h (k 128..255), gate g, 8 col-tiles
    short8v bwh[8][4], bwx[8][4];
    #pragma unroll
    for (int n = 0; n < 8; ++n) {
        const int col = n * 16 + l15;
        #pragma unroll
        for (int ks = 0; ks < 4; ++ks) {
            short8v wh, wx;
            #pragma unroll
            for (int j = 0; j < 8; ++j) {
                const int k = ks * 32 + kg * 8 + j;
                wx[j] = (short)f2bf(Wsel[(size_t)k * HID + col]);
                wh[j] = (short)f2bf(Wsel[(size_t)(128 + k) * HID + col]);
            }
            bwx[n][ks] = wx;
            bwh[n][ks] = wh;
        }
    }
    float biasr[8];
    #pragma unroll
    for (int n = 0; n < 8; ++n) biasr[n] = bsel[n * 16 + l15];

    if (tid < 128) ((unsigned*)h_bf)[tid] = 0u;   // h0 = 0

    const int crow = wid >> 1;                    // Phase-B (row,col) per lane
    const int ccol = (wid & 1) * 64 + lane;
    const int ca0  = kg * 32 + l15;               // Phase-A activation cols
    float c_reg = 0.f, h_last = 0.f;

    // x_win staging geometry: row m = step_local*2 + batch_row
    const int sm  = tid >> 4;                     // m 0..15
    const int sbl = tid & 15;                     // 16B block 0..15
    const size_t xrow_off = ((size_t)(b0 + (sm & 1))) * HID + sbl * 8;
    const int xw_off = (sbl * 16) ^ ((sm & 7) << 4);   // swizzled byte offset
    const int xsw = (l15 & 7) << 4;                    // read-side swizzle

#define STAGE_XWIN(buf, s0) do {                                                   \
    const float* xp_ = X + ((size_t)((s0) + (sm >> 1)) * BATCH) * HID + xrow_off;  \
    float4v a_ = *(const float4v*)xp_;                                             \
    float4v b_ = *(const float4v*)(xp_ + 4);                                       \
    ushort8v o_;                                                                   \
    o_[0]=f2bf(a_[0]); o_[1]=f2bf(a_[1]); o_[2]=f2bf(a_[2]); o_[3]=f2bf(a_[3]);    \
    o_[4]=f2bf(b_[0]); o_[5]=f2bf(b_[1]); o_[6]=f2bf(b_[2]); o_[7]=f2bf(b_[3]);    \
    *(ushort8v*)((char*)&x_win[buf][sm][0] + xw_off) = o_;                         \
} while (0)

#define LOAD_AX(buf) do {                                                          \
    const char* xb_ = (const char*)&x_win[buf][0][0] + l15 * 256;                  \
    ax[0] = *(const short8v*)(xb_ + ((      kg * 16) ^ xsw));                      \
    ax[1] = *(const short8v*)(xb_ + (( 64 + kg * 16) ^ xsw));                      \
    ax[2] = *(const short8v*)(xb_ + ((128 + kg * 16) ^ xsw));                      \
    ax[3] = *(const short8v*)(xb_ + ((192 + kg * 16) ^ xsw));                      \
} while (0)

// 4-MFMA x-tile N of next window; D: lane(kg,l15) reg j -> step kg*2+(j>>1),
// row j&1, col N*16+l15. Writes bf16 row-pairs into zring.
#define XTILE(N) do {                                                              \
    float4v xa_;                                                                   \
    xa_[0] = biasr[N]; xa_[1] = biasr[N]; xa_[2] = biasr[N]; xa_[3] = biasr[N];    \
    xa_ = __builtin_amdgcn_mfma_f32_16x16x32_bf16(ax[0], bwx[N][0], xa_, 0, 0, 0); \
    xa_ = __builtin_amdgcn_mfma_f32_16x16x32_bf16(ax[1], bwx[N][1], xa_, 0, 0, 0); \
    xa_ = __builtin_amdgcn_mfma_f32_16x16x32_bf16(ax[2], bwx[N][2], xa_, 0, 0, 0); \
    xa_ = __builtin_amdgcn_mfma_f32_16x16x32_bf16(ax[3], bwx[N][3], xa_, 0, 0, 0); \
    const int se_ = (bnext + kg * 2) & 15;                                         \
    const int cs_ = (N) * 16 + l15;                                                \
    zr_lds[zswz(se_,     g, cs_)] = packbf(xa_[0], xa_[1]);                        \
    zr_lds[zswz(se_ + 1, g, cs_)] = packbf(xa_[2], xa_[3]);                        \
} while (0)

    short8v ax[4];            // current-window x A-frags (held across 8 steps)
    float4v xg0 = {}, xg1 = {};   // staged x (issued w==0, written w==4)

    // ---- prologue: x_win[0]<-x[0..7], x_win[1]<-x[8..15]; slots 0..7 ----
    STAGE_XWIN(0, 0);
    STAGE_XWIN(1, 8);
    BAR();
    LOAD_AX(0);
    {
        float4v pacc[8];
        #pragma unroll
        for (int n = 0; n < 8; ++n)
            #pragma unroll
            for (int j = 0; j < 4; ++j) pacc[n][j] = biasr[n];
        #pragma unroll
        for (int ks = 0; ks < 4; ++ks)
            #pragma unroll
            for (int n = 0; n < 8; ++n)
                pacc[n] = __builtin_amdgcn_mfma_f32_16x16x32_bf16(ax[ks], bwx[n][ks], pacc[n], 0, 0, 0);
        #pragma unroll
        for (int n = 0; n < 8; ++n) {
            const int se_ = kg * 2;
            const int cs_ = n * 16 + l15;
            zr_lds[zswz(se_,     g, cs_)] = packbf(pacc[n][0], pacc[n][1]);
            zr_lds[zswz(se_ + 1, g, cs_)] = packbf(pacc[n][2], pacc[n][3]);
        }
    }
    BAR();

    #pragma unroll 1
    for (int t = 0; t < SEQ; ++t) {
        const int w = t & 7;
        const int W = t >> 3;
        const int bnext = (t & ~7) + 8;       // first step of next window

        // ---------------- Phase A ----------------
        // early LDS reads (latency hides under MFMA burst)
        const unsigned zp0 = zr_lds[zswz(t & 15, g, ca0)];
        const unsigned zp1 = zr_lds[zswz(t & 15, g, ca0 + 16)];
        short8v ah[4];
        #pragma unroll
        for (int ks = 0; ks < 4; ++ks)
            ah[ks] = *(const short8v*)&h_bf[l15 & 1][ks * 32 + kg * 8];

        if (w == 0) {
            if (bnext < SEQ) LOAD_AX((W + 1) & 1);
            if (bnext + 8 < SEQ) {            // issue global x loads (consumed w==4)
                const float* xp = X + ((size_t)(bnext + 8 + (sm >> 1)) * BATCH) * HID + xrow_off;
                xg0 = *(const float4v*)xp;
                xg1 = *(const float4v*)(xp + 4);
            }
        }

        // h-GEMM: 32 MFMA, rows replicated in M
        float4v acc[8];
        #pragma unroll
        for (int n = 0; n < 8; ++n)
            #pragma unroll
            for (int j = 0; j < 4; ++j) acc[n][j] = 0.f;
        #pragma unroll
        for (int ks = 0; ks < 4; ++ks)
            #pragma unroll
            for (int n = 0; n < 8; ++n)
                acc[n] = __builtin_amdgcn_mfma_f32_16x16x32_bf16(ah[ks], bwh[n][ks], acc[n], 0, 0, 0);

        // x-tile of next window (4 MFMA, off-chain)
        if (bnext < SEQ) {
            switch (w) {
                case 0: XTILE(0); break;
                case 1: XTILE(1); break;
                case 2: XTILE(2); break;
                case 3: XTILE(3); break;
                case 4: XTILE(4); break;
                case 5: XTILE(5); break;
                case 6: XTILE(6); break;
                default: XTILE(7); break;
            }
        }

        // z add + activation (tiles n=2kg,2kg+1; reg parity = batch row)
        float s0r0 = ((kg == 0) ? acc[0][0] : (kg == 1) ? acc[2][0]
                    : (kg == 2) ? acc[4][0] : acc[6][0]) + bf2f((unsigned short)(zp0 & 0xffffu));
        float s0r1 = ((kg == 0) ? acc[0][1] : (kg == 1) ? acc[2][1]
                    : (kg == 2) ? acc[4][1] : acc[6][1]) + bf2f((unsigned short)(zp0 >> 16));
        float s1r0 = ((kg == 0) ? acc[1][0] : (kg == 1) ? acc[3][0]
                    : (kg == 2) ? acc[5][0] : acc[7][0]) + bf2f((unsigned short)(zp1 & 0xffffu));
        float s1r1 = ((kg == 0) ? acc[1][1] : (kg == 1) ? acc[3][1]
                    : (kg == 2) ? acc[5][1] : acc[7][1]) + bf2f((unsigned short)(zp1 >> 16));

        float v00, v01, v10, v11;
        if (g == 0) {
            float Fa0, Fb0, Fa1, Fb1;
            fscan(fast_cos(s0r0), fast_cos(s1r0), kg, Fa0, Fb0);
            fscan(fast_cos(s0r1), fast_cos(s1r1), kg, Fa1, Fb1);
            v00 = (Fa0 + 1.f) * 0.5f; v01 = (Fb0 + 1.f) * 0.5f;
            v10 = (Fa1 + 1.f) * 0.5f; v11 = (Fb1 + 1.f) * 0.5f;
        } else if (g == 1) {
            v00 = (fast_cos(s0r0) + 1.f) * .5f; v01 = (fast_cos(s1r0) + 1.f) * .5f;
            v10 = (fast_cos(s0r1) + 1.f) * .5f; v11 = (fast_cos(s1r1) + 1.f) * .5f;
        } else if (g == 2) {
            v00 = fast_tanh(s0r0); v01 = fast_tanh(s1r0);
            v10 = fast_tanh(s0r1); v11 = fast_tanh(s1r1);
        } else {
            v00 = fast_sigmoid(s0r0); v01 = fast_sigmoid(s1r0);
            v10 = fast_sigmoid(s0r1); v11 = fast_sigmoid(s1r1);
        }
        ga_lds[gswz(0, g, ca0)]      = v00;
        ga_lds[gswz(0, g, ca0 + 16)] = v01;
        ga_lds[gswz(1, g, ca0)]      = v10;
        ga_lds[gswz(1, g, ca0 + 16)] = v11;

        BAR();  // S1: gact + zring tile published

        // ---------------- Phase B ----------------
        const float fv = ga_lds[gswz(crow, 0, ccol)];
        const float iv = ga_lds[gswz(crow, 1, ccol)];
        const float gv = ga_lds[gswz(crow, 2, ccol)];
        const float ov = ga_lds[gswz(crow, 3, ccol)];
        const float cn = fmaf(fv, c_reg, iv * gv);
        const float hn = ov * fast_tanh(cn);
        c_reg = cn; h_last = hn;
        h_bf[crow][ccol] = f2bf(hn);
        out[((size_t)t * BATCH + b0 + crow) * HID + ccol] = hn;

        if (w == 4 && bnext + 8 < SEQ) {
            // publish staged x (loaded at w==0) for window W+2
            ushort8v o_;
            o_[0]=f2bf(xg0[0]); o_[1]=f2bf(xg0[1]); o_[2]=f2bf(xg0[2]); o_[3]=f2bf(xg0[3]);
            o_[4]=f2bf(xg1[0]); o_[5]=f2bf(xg1[1]); o_[6]=f2bf(xg1[2]); o_[7]=f2bf(xg1[3]);
            *(ushort8v*)((char*)&x_win[W & 1][sm][0] + xw_off) = o_;
        }
        BAR();  // S2: h_bf (and x_win) ready
    }

    // final hx/cx tails (each lane holds its (row,col) last-step values)
    {
        const size_t base = (size_t)SEQ * BATCH * HID;
        const size_t ro = (size_t)(b0 + crow) * HID + ccol;
        out[base + ro] = h_last;
        out[base + (size_t)BATCH * HID + ro] = c_reg;
    }
#undef STAGE_XWIN
#undef LOAD_AX
#undef XTILE
}

// ---------------------------------------------------------------------------
extern "C" void kernel_launch(void* const* d_in, const int* in_sizes, int n_in,
                              void* d_out, int out_size, void* d_ws, size_t ws_size,
                              hipStream_t stream) {
    const float* X  = (const float*)d_in[0];
    const float* Wf = (const float*)d_in[1];
    const float* bf = (const float*)d_in[2];
    const float* Wi = (const float*)d_in[3];
    const float* bi = (const float*)d_in[4];
    const float* Wg = (const float*)d_in[5];
    const float* bg = (const float*)d_in[6];
    const float* Wo = (const float*)d_in[7];
    const float* bo = (const float*)d_in[8];
    float* out = (float*)d_out;
    (void)d_ws; (void)ws_size;

    qlstm_fused<<<BATCH / 2, 256, 0, stream>>>(
        X, Wf, bf, Wi, bi, Wg, bg, Wo, bo, out);
}

// Round 14
// 1039.577 us; speedup vs baseline: 1.5580x; 1.5580x over previous
//
#include <hip/hip_runtime.h>

#define SEQ   1024
#define BATCH 512
#define HID   128

typedef __attribute__((ext_vector_type(8))) short          short8v;
typedef __attribute__((ext_vector_type(4))) float          float4v;
typedef __attribute__((ext_vector_type(8))) unsigned short ushort8v;

__device__ __forceinline__ unsigned short f2bf(float f) {
    union { float f; unsigned u; } v; v.f = f;
    return (unsigned short)((v.u + 0x7fffu + ((v.u >> 16) & 1u)) >> 16);
}
__device__ __forceinline__ float bf2f(unsigned short u) {
    union { unsigned u; float f; } v; v.u = ((unsigned)u) << 16;
    return v.f;
}
__device__ __forceinline__ unsigned packbf(float a, float b) {
    return (unsigned)f2bf(a) | ((unsigned)f2bf(b) << 16);
}
__device__ __forceinline__ float fast_cos(float x) {
    return __builtin_amdgcn_cosf(x * 0.15915494309189535f);   // v_cos takes revolutions
}
__device__ __forceinline__ float fast_sigmoid(float x) {
    return __builtin_amdgcn_rcpf(1.0f + __builtin_amdgcn_exp2f(-1.4426950408889634f * x));
}
__device__ __forceinline__ float fast_tanh(float x) {
    return 1.0f - 2.0f * __builtin_amdgcn_rcpf(1.0f + __builtin_amdgcn_exp2f(2.8853900817779268f * x));
}
template<int CTRL, int RM>
__device__ __forceinline__ float dpp1(float v) {
    union { float f; int i; } s, o, r;
    s.f = v; o.f = 1.0f;
    r.i = __builtin_amdgcn_update_dpp(o.i, s.i, CTRL, RM, 0xf, false);
    return r.f;
}
#define BAR() do { asm volatile("s_waitcnt lgkmcnt(0)" ::: "memory");  \
                   __builtin_amdgcn_s_barrier();                       \
                   __builtin_amdgcn_sched_barrier(0); } while (0)

// in-wave inclusive cumprod over 128 cols held as (a = col kg*32+l15,
// b = col kg*32+16+l15). 16-lane DPP scans + block totals via shfl. (R12-verified)
__device__ __forceinline__ void fscan(float a, float b, int kg,
                                      float& Fa, float& Fb) {
    float Sa = a, Sb = b;
    Sa *= dpp1<0x111, 0xf>(Sa);  Sb *= dpp1<0x111, 0xf>(Sb);   // row_shr:1
    Sa *= dpp1<0x112, 0xf>(Sa);  Sb *= dpp1<0x112, 0xf>(Sb);   // row_shr:2
    Sa *= dpp1<0x114, 0xf>(Sa);  Sb *= dpp1<0x114, 0xf>(Sb);   // row_shr:4
    Sa *= dpp1<0x118, 0xf>(Sa);  Sb *= dpp1<0x118, 0xf>(Sb);   // row_shr:8
    const float T0a = __shfl(Sa, 15), T0b = __shfl(Sb, 15);
    const float T1a = __shfl(Sa, 31), T1b = __shfl(Sb, 31);
    const float T2a = __shfl(Sa, 47), T2b = __shfl(Sb, 47);
    const float Taown = __shfl(Sa, kg * 16 + 15);
    const float p0 = T0a * T0b, p1 = T1a * T1b, p2 = T2a * T2b;
    const float rp = (kg == 0) ? 1.f : (kg == 1) ? p0
                   : (kg == 2) ? p0 * p1 : p0 * p1 * p2;
    Fa = rp * Sa;
    Fb = rp * Taown * Sb;
}

// LDS swizzles (R13-verified): bijective in col; hot accesses <=2-way.
__device__ __forceinline__ int zswz(int slot, int g, int c) {
    return slot * 512 + g * 128 + (c ^ ((c >> 5) << 4) ^ ((slot & 2) << 3));
}
__device__ __forceinline__ int gswz(int row, int g, int c) {
    return row * 512 + g * 128 + (c ^ ((c >> 5) << 4));
}

// ---------------------------------------------------------------------------
// ONE persistent kernel. 256 WGs x 512 thr (8 waves, 2/SIMD), 2 rows/WG, 1 WG/CU.
// Waves 0-3 CONSUMERS (gate g=wid): h-GEMM (rows replicated in M, W_h in regs,
//   z from bf16 ring) + in-register activation (wave0 = full fscan) -> gact.
// Waves 4-7 PRODUCERS (gate g=wid-4): x-window GEMM — 16 M-slots = 8 steps x
//   2 rows, ONE 4-MFMA tile per step (amortized 4 MFMA/step, was 32 in R12).
//   ax frags reloaded once per window (w==0); x staged global->reg (w==0) ->
//   x_win (w==4, Phase B). All mappings verbatim from R13 (refcheck'd).
// Phase A: consumer MFMA (setprio) + act  ||  producer tile; S1.
// Phase B: consumer cell update (1 (row,col)/lane, 4 waves)  ||  wave-4 x_win
//   publish; S2.
// ---------------------------------------------------------------------------
__global__ __launch_bounds__(512, 1) void qlstm_fused(
    const float* __restrict__ X,
    const float* __restrict__ Wf, const float* __restrict__ bfp,
    const float* __restrict__ Wi, const float* __restrict__ bip,
    const float* __restrict__ Wg, const float* __restrict__ bgp,
    const float* __restrict__ Wo, const float* __restrict__ bop,
    float* __restrict__ out)
{
    __shared__ unsigned zr_lds[16 * 4 * 128];                 // 32 KB bf16 row-pair z ring
    __shared__ float    ga_lds[2 * 4 * 128];                  // 4 KB activated gates
    __shared__ alignas(16) unsigned short h_bf[2][HID];       // 512 B
    __shared__ alignas(16) unsigned short x_win[2][16][HID];  // 8 KB x window dbuf

    const int tid = threadIdx.x, lane = tid & 63, wid = tid >> 6;
    const int l15 = lane & 15, kg = lane >> 4;
    const int b0 = blockIdx.x * 2;
    const bool prod = (wid >= 4);
    const int g = wid & 3;
    const float* Wsel = (g == 0) ? Wf : (g == 1) ? Wi : (g == 2) ? Wg : Wo;
    const float* bsel = (g == 0) ? bfp : (g == 1) ? bip : (g == 2) ? bgp : bop;

    // ONE weight set per wave: consumers W_h (k 128..255), producers W_x (k 0..127)
    short8v bw[8][4];
    {
        const int kbase = prod ? 0 : 128;
        #pragma unroll
        for (int n = 0; n < 8; ++n) {
            const int col = n * 16 + l15;
            #pragma unroll
            for (int ks = 0; ks < 4; ++ks) {
                const int k0 = kbase + ks * 32 + kg * 8;
                short8v a;
                #pragma unroll
                for (int j = 0; j < 8; ++j)
                    a[j] = (short)f2bf(Wsel[(size_t)(k0 + j) * HID + col]);
                bw[n][ks] = a;
            }
        }
    }
    float biasr[8];
    #pragma unroll
    for (int n = 0; n < 8; ++n) biasr[n] = prod ? bsel[n * 16 + l15] : 0.f;

    if (tid < 128) ((unsigned*)h_bf)[tid] = 0u;   // h0 = 0

    // consumer Phase-B cell geometry (1 (row,col)/lane across waves 0-3)
    const int crow = wid >> 1;
    const int ccol = (wid & 1) * 64 + lane;
    const int ca0  = kg * 32 + l15;
    float c_reg = 0.f, h_last = 0.f;

    // producer x_win staging geometry (256 producer threads): row m = 2*step+row
    const int pt  = tid - 256;                 // 0..255 for producers
    const int sm  = (pt >> 4) & 15;            // m 0..15
    const int sbl = pt & 15;                   // 16B block
    const size_t xrow_off = ((size_t)(b0 + (sm & 1))) * HID + sbl * 8;
    const int xw_off = (sbl * 16) ^ ((sm & 7) << 4);
    const int xsw = (l15 & 7) << 4;

#define STAGE_XWIN(buf, s0) do {                                                   \
    const float* xp_ = X + ((size_t)((s0) + (sm >> 1)) * BATCH) * HID + xrow_off;  \
    float4v a_ = *(const float4v*)xp_;                                             \
    float4v b_ = *(const float4v*)(xp_ + 4);                                       \
    ushort8v o_;                                                                   \
    o_[0]=f2bf(a_[0]); o_[1]=f2bf(a_[1]); o_[2]=f2bf(a_[2]); o_[3]=f2bf(a_[3]);    \
    o_[4]=f2bf(b_[0]); o_[5]=f2bf(b_[1]); o_[6]=f2bf(b_[2]); o_[7]=f2bf(b_[3]);    \
    *(ushort8v*)((char*)&x_win[buf][sm][0] + xw_off) = o_;                         \
} while (0)

#define LOAD_AX(buf) do {                                                          \
    const char* xb_ = (const char*)&x_win[buf][0][0] + l15 * 256;                  \
    ax[0] = *(const short8v*)(xb_ + ((      kg * 16) ^ xsw));                      \
    ax[1] = *(const short8v*)(xb_ + (( 64 + kg * 16) ^ xsw));                      \
    ax[2] = *(const short8v*)(xb_ + ((128 + kg * 16) ^ xsw));                      \
    ax[3] = *(const short8v*)(xb_ + ((192 + kg * 16) ^ xsw));                      \
} while (0)

// 4-MFMA x-tile N of next window; lane(kg,l15) reg j -> step kg*2+(j>>1),
// row j&1, col N*16+l15. (R13-verified mapping)
#define XTILE(N) do {                                                              \
    float4v xa_;                                                                   \
    xa_[0] = biasr[N]; xa_[1] = biasr[N]; xa_[2] = biasr[N]; xa_[3] = biasr[N];    \
    xa_ = __builtin_amdgcn_mfma_f32_16x16x32_bf16(ax[0], bw[N][0], xa_, 0, 0, 0);  \
    xa_ = __builtin_amdgcn_mfma_f32_16x16x32_bf16(ax[1], bw[N][1], xa_, 0, 0, 0);  \
    xa_ = __builtin_amdgcn_mfma_f32_16x16x32_bf16(ax[2], bw[N][2], xa_, 0, 0, 0);  \
    xa_ = __builtin_amdgcn_mfma_f32_16x16x32_bf16(ax[3], bw[N][3], xa_, 0, 0, 0);  \
    const int se_ = (bnext + kg * 2) & 15;                                         \
    const int cs_ = (N) * 16 + l15;                                                \
    zr_lds[zswz(se_,     g, cs_)] = packbf(xa_[0], xa_[1]);                        \
    zr_lds[zswz(se_ + 1, g, cs_)] = packbf(xa_[2], xa_[3]);                        \
} while (0)

    short8v ax[4] = {};           // producer: current-window x A-frags
    float4v xg0 = {}, xg1 = {};   // producer: staged x (issued w==0, written w==4)

    // ---- prologue: x_win[0]<-x[0..7], x_win[1]<-x[8..15]; z slots 0..7 ----
    if (prod) { STAGE_XWIN(0, 0); STAGE_XWIN(1, 8); }
    BAR();
    if (prod) {
        LOAD_AX(0);
        float4v pacc[8];
        #pragma unroll
        for (int n = 0; n < 8; ++n)
            #pragma unroll
            for (int j = 0; j < 4; ++j) pacc[n][j] = biasr[n];
        #pragma unroll
        for (int ks = 0; ks < 4; ++ks)
            #pragma unroll
            for (int n = 0; n < 8; ++n)
                pacc[n] = __builtin_amdgcn_mfma_f32_16x16x32_bf16(ax[ks], bw[n][ks], pacc[n], 0, 0, 0);
        #pragma unroll
        for (int n = 0; n < 8; ++n) {
            const int se_ = kg * 2;
            const int cs_ = n * 16 + l15;
            zr_lds[zswz(se_,     g, cs_)] = packbf(pacc[n][0], pacc[n][1]);
            zr_lds[zswz(se_ + 1, g, cs_)] = packbf(pacc[n][2], pacc[n][3]);
        }
    }
    BAR();

    #pragma unroll 1
    for (int t = 0; t < SEQ; ++t) {
        const int w = t & 7;
        const int W = t >> 3;
        const int bnext = (t & ~7) + 8;

        // ---------------- Phase A ----------------
        if (!prod) {
            // early LDS reads (latency hides under MFMA burst)
            const unsigned zp0 = zr_lds[zswz(t & 15, g, ca0)];
            const unsigned zp1 = zr_lds[zswz(t & 15, g, ca0 + 16)];
            short8v ah[4];
            #pragma unroll
            for (int ks = 0; ks < 4; ++ks)
                ah[ks] = *(const short8v*)&h_bf[l15 & 1][ks * 32 + kg * 8];

            float4v acc[8];
            #pragma unroll
            for (int n = 0; n < 8; ++n)
                #pragma unroll
                for (int j = 0; j < 4; ++j) acc[n][j] = 0.f;

            __builtin_amdgcn_s_setprio(1);
            #pragma unroll
            for (int ks = 0; ks < 4; ++ks)
                #pragma unroll
                for (int n = 0; n < 8; ++n)
                    acc[n] = __builtin_amdgcn_mfma_f32_16x16x32_bf16(ah[ks], bw[n][ks], acc[n], 0, 0, 0);
            __builtin_amdgcn_s_setprio(0);

            // tiles n=2kg,2kg+1; reg parity = batch row
            float s0r0 = ((kg == 0) ? acc[0][0] : (kg == 1) ? acc[2][0]
                        : (kg == 2) ? acc[4][0] : acc[6][0]) + bf2f((unsigned short)(zp0 & 0xffffu));
            float s0r1 = ((kg == 0) ? acc[0][1] : (kg == 1) ? acc[2][1]
                        : (kg == 2) ? acc[4][1] : acc[6][1]) + bf2f((unsigned short)(zp0 >> 16));
            float s1r0 = ((kg == 0) ? acc[1][0] : (kg == 1) ? acc[3][0]
                        : (kg == 2) ? acc[5][0] : acc[7][0]) + bf2f((unsigned short)(zp1 & 0xffffu));
            float s1r1 = ((kg == 0) ? acc[1][1] : (kg == 1) ? acc[3][1]
                        : (kg == 2) ? acc[5][1] : acc[7][1]) + bf2f((unsigned short)(zp1 >> 16));

            float v00, v01, v10, v11;
            if (g == 0) {
                float Fa0, Fb0, Fa1, Fb1;
                fscan(fast_cos(s0r0), fast_cos(s1r0), kg, Fa0, Fb0);
                fscan(fast_cos(s0r1), fast_cos(s1r1), kg, Fa1, Fb1);
                v00 = (Fa0 + 1.f) * 0.5f; v01 = (Fb0 + 1.f) * 0.5f;
                v10 = (Fa1 + 1.f) * 0.5f; v11 = (Fb1 + 1.f) * 0.5f;
            } else if (g == 1) {
                v00 = (fast_cos(s0r0) + 1.f) * .5f; v01 = (fast_cos(s1r0) + 1.f) * .5f;
                v10 = (fast_cos(s0r1) + 1.f) * .5f; v11 = (fast_cos(s1r1) + 1.f) * .5f;
            } else if (g == 2) {
                v00 = fast_tanh(s0r0); v01 = fast_tanh(s1r0);
                v10 = fast_tanh(s0r1); v11 = fast_tanh(s1r1);
            } else {
                v00 = fast_sigmoid(s0r0); v01 = fast_sigmoid(s1r0);
                v10 = fast_sigmoid(s0r1); v11 = fast_sigmoid(s1r1);
            }
            ga_lds[gswz(0, g, ca0)]      = v00;
            ga_lds[gswz(0, g, ca0 + 16)] = v01;
            ga_lds[gswz(1, g, ca0)]      = v10;
            ga_lds[gswz(1, g, ca0 + 16)] = v11;
        } else {
            if (w == 0) {
                if (bnext < SEQ) LOAD_AX((W + 1) & 1);
                if (bnext + 8 < SEQ) {   // issue global x loads (consumed w==4)
                    const float* xp = X + ((size_t)(bnext + 8 + (sm >> 1)) * BATCH) * HID + xrow_off;
                    xg0 = *(const float4v*)xp;
                    xg1 = *(const float4v*)(xp + 4);
                }
            }
            if (bnext < SEQ) {           // one 4-MFMA tile of next window
                switch (w) {
                    case 0: XTILE(0); break;
                    case 1: XTILE(1); break;
                    case 2: XTILE(2); break;
                    case 3: XTILE(3); break;
                    case 4: XTILE(4); break;
                    case 5: XTILE(5); break;
                    case 6: XTILE(6); break;
                    default: XTILE(7); break;
                }
            }
        }
        BAR();  // S1: gact + zring tile published

        // ---------------- Phase B ----------------
        if (!prod) {
            const float fv = ga_lds[gswz(crow, 0, ccol)];
            const float iv = ga_lds[gswz(crow, 1, ccol)];
            const float gv = ga_lds[gswz(crow, 2, ccol)];
            const float ov = ga_lds[gswz(crow, 3, ccol)];
            const float cn = fmaf(fv, c_reg, iv * gv);
            const float hn = ov * fast_tanh(cn);
            c_reg = cn; h_last = hn;
            h_bf[crow][ccol] = f2bf(hn);
            out[((size_t)t * BATCH + b0 + crow) * HID + ccol] = hn;
        } else if (w == 4 && bnext + 8 < SEQ) {
            // publish staged x (loaded at w==0) for window W+2
            ushort8v o_;
            o_[0]=f2bf(xg0[0]); o_[1]=f2bf(xg0[1]); o_[2]=f2bf(xg0[2]); o_[3]=f2bf(xg0[3]);
            o_[4]=f2bf(xg1[0]); o_[5]=f2bf(xg1[1]); o_[6]=f2bf(xg1[2]); o_[7]=f2bf(xg1[3]);
            *(ushort8v*)((char*)&x_win[W & 1][sm][0] + xw_off) = o_;
        }
        BAR();  // S2: h_bf (and x_win) ready
    }

    // final hx/cx tails (consumer lanes hold their (row,col) last-step values)
    if (!prod) {
        const size_t base = (size_t)SEQ * BATCH * HID;
        const size_t ro = (size_t)(b0 + crow) * HID + ccol;
        out[base + ro] = h_last;
        out[base + (size_t)BATCH * HID + ro] = c_reg;
    }
#undef STAGE_XWIN
#undef LOAD_AX
#undef XTILE
}

// ---------------------------------------------------------------------------
extern "C" void kernel_launch(void* const* d_in, const int* in_sizes, int n_in,
                              void* d_out, int out_size, void* d_ws, size_t ws_size,
                              hipStream_t stream) {
    const float* X  = (const float*)d_in[0];
    const float* Wf = (const float*)d_in[1];
    const float* bf = (const float*)d_in[2];
    const float* Wi = (const float*)d_in[3];
    const float* bi = (const float*)d_in[4];
    const float* Wg = (const float*)d_in[5];
    const float* bg = (const float*)d_in[6];
    const float* Wo = (const float*)d_in[7];
    const float* bo = (const float*)d_in[8];
    float* out = (float*)d_out;
    (void)d_ws; (void)ws_size;

    qlstm_fused<<<BATCH / 2, 512, 0, stream>>>(
        X, Wf, bf, Wi, bi, Wg, bg, Wo, bo, out);
}